// Round 11
// baseline (270.581 us; speedup 1.0000x reference)
//
#include <hip/hip_runtime.h>
#include <hip/hip_bf16.h>

#define NF 128
#define HRANGE 8192   // out-degree hist: nodes per LDS range (32 KB)
#define HB 32         // out-degree hist: edge-chunk blocks per range
#define EPB 4096      // edges per binA block
#define CAP 6144      // per-bucket region capacity (mean 4096, +32 sigma)

// ---------------- init ----------------
__global__ void k_init(int* __restrict__ cntO, int* __restrict__ bucketCnt,
                       int* __restrict__ rowoff, int N, int E) {
  int i = blockIdx.x * 256 + threadIdx.x;
  if (i < N) cntO[i] = 0;
  if (i < 512) bucketCnt[i] = 0;
  if (i == 0) rowoff[N] = E;
}

// ---------------- out-degree histogram (LDS-privatized, multi-range) ----------------
__global__ __launch_bounds__(256) void k_hist(const int* __restrict__ src,
                                              int* __restrict__ cntO, int N, int E) {
  __shared__ int smem[HRANGE];
  int b = blockIdx.x;
  int r = b / HB, c = b % HB;
  int r0 = r * HRANGE;
  int r1 = r0 + HRANGE; if (r1 > N) r1 = N;
  for (int k = threadIdx.x; k < HRANGE; k += 256) smem[k] = 0;
  __syncthreads();
  int chunk = (E + HB - 1) / HB;
  int e0 = c * chunk;
  int e1 = e0 + chunk; if (e1 > E) e1 = E;
  for (int e = e0 + threadIdx.x; e < e1; e += 256) {
    int s = src[e];
    if (s >= r0 && s < r1) atomicAdd(&smem[s - r0], 1);
  }
  __syncthreads();
  for (int k = threadIdx.x; k < r1 - r0; k += 256) {
    int v = smem[k];
    if (v) atomicAdd(&cntO[r0 + k], v);
  }
}

// ---------------- binA: LDS-staged binning of edges into 256-node buckets ----------------
__global__ __launch_bounds__(256) void k_binA(const int* __restrict__ src,
                                              const int* __restrict__ dst,
                                              int* __restrict__ bucketCnt,
                                              int2* __restrict__ region, int E) {
  __shared__ int cnt[512], scanv[512], cur[512], gb[512], s1[256];
  __shared__ int2 st[EPB];  // 32 KB
  int tid = threadIdx.x;
  int b0 = blockIdx.x * EPB;
  int n = E - b0; if (n > EPB) n = EPB;

  for (int k = tid; k < 512; k += 256) cnt[k] = 0;
  __syncthreads();
  for (int k = tid; k < n; k += 256) atomicAdd(&cnt[dst[b0 + k] >> 8], 1);
  __syncthreads();

  int c0 = cnt[2 * tid], c1 = cnt[2 * tid + 1];
  s1[tid] = c0 + c1;
  __syncthreads();
  for (int off = 1; off < 256; off <<= 1) {
    int v = (tid >= off) ? s1[tid - off] : 0;
    __syncthreads();
    s1[tid] += v;
    __syncthreads();
  }
  int excl = tid ? s1[tid - 1] : 0;
  scanv[2 * tid] = excl;
  scanv[2 * tid + 1] = excl + c0;
  cur[2 * tid] = excl;
  cur[2 * tid + 1] = excl + c0;
  gb[2 * tid]     = c0 ? atomicAdd(&bucketCnt[2 * tid], c0) : 0;
  gb[2 * tid + 1] = c1 ? atomicAdd(&bucketCnt[2 * tid + 1], c1) : 0;
  __syncthreads();

  for (int k = tid; k < n; k += 256) {
    int d = dst[b0 + k], s = src[b0 + k];
    int p = atomicAdd(&cur[d >> 8], 1);
    st[p] = make_int2(d, s);
  }
  __syncthreads();
  for (int k = tid; k < n; k += 256) {
    int2 e = st[k];
    int b = e.x >> 8;
    int gp = gb[b] + (k - scanv[b]);
    if (gp < CAP) region[(size_t)b * CAP + gp] = e;
  }
}

// ---------------- bscan: exclusive scan of bucket counts -> csr bases ----------------
__global__ __launch_bounds__(256) void k_bscan(const int* __restrict__ bucketCnt,
                                               int* __restrict__ bucketBase, int NB) {
  __shared__ int s1[256];
  int tid = threadIdx.x;
  int c0 = (2 * tid < NB) ? bucketCnt[2 * tid] : 0;
  int c1 = (2 * tid + 1 < NB) ? bucketCnt[2 * tid + 1] : 0;
  s1[tid] = c0 + c1;
  __syncthreads();
  for (int off = 1; off < 256; off <<= 1) {
    int v = (tid >= off) ? s1[tid - off] : 0;
    __syncthreads();
    s1[tid] += v;
    __syncthreads();
  }
  int excl = tid ? s1[tid - 1] : 0;
  if (2 * tid < NB) bucketBase[2 * tid] = excl;
  if (2 * tid + 1 < NB) bucketBase[2 * tid + 1] = excl + c0;
}

// ---------------- binB: per-bucket counting sort -> csr + rowoff + invI ----------------
__global__ __launch_bounds__(256) void k_binB(const int2* __restrict__ region,
                                              const int* __restrict__ bucketCnt,
                                              const int* __restrict__ bucketBase,
                                              int* __restrict__ csr,
                                              int* __restrict__ rowoff,
                                              float* __restrict__ invI, int N) {
  __shared__ int hist[256], incl[256], cur[256];
  int tid = threadIdx.x;
  int b = blockIdx.x;
  int base = b << 8;
  int nN = N - base; if (nN > 256) nN = 256;
  int cntb = bucketCnt[b]; if (cntb > CAP) cntb = CAP;
  const int2* reg = region + (size_t)b * CAP;

  hist[tid] = 0;
  __syncthreads();
  for (int k = tid; k < cntb; k += 256) atomicAdd(&hist[reg[k].x - base], 1);
  __syncthreads();
  int h = hist[tid];
  incl[tid] = h;
  __syncthreads();
  for (int off = 1; off < 256; off <<= 1) {
    int v = (tid >= off) ? incl[tid - off] : 0;
    __syncthreads();
    incl[tid] += v;
    __syncthreads();
  }
  int startt = incl[tid] - h;  // exclusive
  int csrBase = bucketBase[b];
  if (tid < nN) {
    rowoff[base + tid] = csrBase + startt;
    invI[base + tid] = rsqrtf(fmaxf((float)h, 1.0f));
  }
  cur[tid] = startt;
  __syncthreads();
  for (int k = tid; k < cntb; k += 256) {
    int2 e = reg[k];
    int p = atomicAdd(&cur[e.x - base], 1);
    csr[csrBase + p] = e.y;  // store within 16KB L2-resident window
  }
}

// ---------------- invO ----------------
__global__ void k_invO(const int* __restrict__ cntO, float* __restrict__ invO, int N) {
  int i = blockIdx.x * 256 + threadIdx.x;
  if (i < N) invO[i] = rsqrtf(fmaxf((float)cntO[i], 1.0f));
}

// ---------------- layer-1 projection: xw = bf16( x @ W1 ), unscaled ----------------
__global__ __launch_bounds__(256) void k_gemm1(const float* __restrict__ x,
                                               const float* __restrict__ W1,
                                               unsigned short* __restrict__ xw, int N) {
  __shared__ float Wl[NF * 64];  // 32 KB
  int tid = threadIdx.x;
  int cb      = (blockIdx.x & 1) * 64;
  int rowbase = (blockIdx.x >> 1) * 64;

  for (int t = tid; t < NF * 16; t += 256) {
    int k = t >> 4, c4 = (t & 15) << 2;
    *(float4*)&Wl[k * 64 + c4] = *(const float4*)&W1[k * NF + cb + c4];
  }
  __syncthreads();

  int c4 = (tid & 15) << 2;
  int rg = tid >> 4;

  const float* xr[4];
#pragma unroll
  for (int r = 0; r < 4; ++r) {
    int row = rowbase + rg + r * 16;
    if (row >= N) row = N - 1;
    xr[r] = x + (size_t)row * NF;
  }

  float4 acc[4];
#pragma unroll
  for (int r = 0; r < 4; ++r) acc[r] = {0.f, 0.f, 0.f, 0.f};

  for (int k0 = 0; k0 < NF; k0 += 4) {
    float4 xv[4];
#pragma unroll
    for (int r = 0; r < 4; ++r) xv[r] = *(const float4*)&xr[r][k0];
#pragma unroll
    for (int j = 0; j < 4; ++j) {
      float4 w = *(float4*)&Wl[(k0 + j) * 64 + c4];
#pragma unroll
      for (int r = 0; r < 4; ++r) {
        float xs = j == 0 ? xv[r].x : j == 1 ? xv[r].y : j == 2 ? xv[r].z : xv[r].w;
        acc[r].x = fmaf(xs, w.x, acc[r].x);
        acc[r].y = fmaf(xs, w.y, acc[r].y);
        acc[r].z = fmaf(xs, w.z, acc[r].z);
        acc[r].w = fmaf(xs, w.w, acc[r].w);
      }
    }
  }

#pragma unroll
  for (int r = 0; r < 4; ++r) {
    int row = rowbase + rg + r * 16;
    if (row < N) {
      __hip_bfloat16 h0 = __float2bfloat16(acc[r].x);
      __hip_bfloat16 h1 = __float2bfloat16(acc[r].y);
      __hip_bfloat16 h2 = __float2bfloat16(acc[r].z);
      __hip_bfloat16 h3 = __float2bfloat16(acc[r].w);
      ushort4 o16;
      o16.x = *(unsigned short*)&h0;
      o16.y = *(unsigned short*)&h1;
      o16.z = *(unsigned short*)&h2;
      o16.w = *(unsigned short*)&h3;
      *(ushort4*)&xw[(size_t)row * NF + cb + c4] = o16;
    }
  }
}

// ---------------- fused gather + layer-2 projection (bf16 rows, invO per edge) ----------------
__global__ __launch_bounds__(256) void k_gather_proj(const unsigned short* __restrict__ xw,
                                                     const int* __restrict__ rowoff,
                                                     const int* __restrict__ csr,
                                                     const float* __restrict__ invI,
                                                     const float* __restrict__ invO,
                                                     const float* __restrict__ b1,
                                                     const float* __restrict__ W2,
                                                     float* __restrict__ h2, int N) {
  int i    = blockIdx.x * 4 + (threadIdx.x >> 6);
  int lane = threadIdx.x & 63;
  int half = lane >> 5;
  int sl   = lane & 31;
  if (i >= N) return;
  int jb = rowoff[i];
  int je = rowoff[i + 1];
  const uint2* xwq = (const uint2*)xw;  // 4 bf16 per uint2, 32 per row
  float a0 = 0.f, a1 = 0.f, a2 = 0.f, a3 = 0.f;

#define BF_FMA(v, o)                                                       \
  do {                                                                     \
    a0 = fmaf(__uint_as_float(((v).x & 0xffffu) << 16), (o), a0);          \
    a1 = fmaf(__uint_as_float((v).x & 0xffff0000u), (o), a1);              \
    a2 = fmaf(__uint_as_float(((v).y & 0xffffu) << 16), (o), a2);          \
    a3 = fmaf(__uint_as_float((v).y & 0xffff0000u), (o), a3);              \
  } while (0)

  int j = jb;
  for (; j + 8 <= je; j += 8) {
    int s0 = csr[j     + half];
    int s1 = csr[j + 2 + half];
    int s2 = csr[j + 4 + half];
    int s3 = csr[j + 6 + half];
    float o0 = invO[s0], o1 = invO[s1], o2 = invO[s2], o3 = invO[s3];
    uint2 v0 = xwq[(size_t)s0 * 32 + sl];
    uint2 v1 = xwq[(size_t)s1 * 32 + sl];
    uint2 v2 = xwq[(size_t)s2 * 32 + sl];
    uint2 v3 = xwq[(size_t)s3 * 32 + sl];
    BF_FMA(v0, o0); BF_FMA(v1, o1); BF_FMA(v2, o2); BF_FMA(v3, o3);
  }
  for (; j < je; j += 2) {
    int e = j + half;
    if (e < je) {
      int s = csr[e];
      float o = invO[s];
      uint2 v = xwq[(size_t)s * 32 + sl];
      BF_FMA(v, o);
    }
  }
#undef BF_FMA

  a0 += __shfl_xor(a0, 32);
  a1 += __shfl_xor(a1, 32);
  a2 += __shfl_xor(a2, 32);
  a3 += __shfl_xor(a3, 32);

  float inI = invI[i];
  int f = sl * 4;
  float4 bb = *(const float4*)&b1[f];
  float4 ww = *(const float4*)&W2[f];
  float u0 = fmaxf(fmaf(a0, inI, bb.x), 0.f);
  float u1 = fmaxf(fmaf(a1, inI, bb.y), 0.f);
  float u2 = fmaxf(fmaf(a2, inI, bb.z), 0.f);
  float u3 = fmaxf(fmaf(a3, inI, bb.w), 0.f);
  float p = u0 * ww.x + u1 * ww.y + u2 * ww.z + u3 * ww.w;
#pragma unroll
  for (int off = 16; off; off >>= 1) p += __shfl_xor(p, off);
  if (lane == 0) h2[i] = p * invO[i];
}

// ---------------- layer-2 gather + epilogue (4 lanes per node) ----------------
__global__ __launch_bounds__(256) void k_gather2(const float* __restrict__ h2,
                                                 const int* __restrict__ rowoff,
                                                 const int* __restrict__ csr,
                                                 const float* __restrict__ invI,
                                                 const float* __restrict__ b2,
                                                 float* __restrict__ out, int N) {
  int i = blockIdx.x * 64 + (threadIdx.x >> 2);
  int q = threadIdx.x & 3;
  if (i >= N) return;
  int jb = rowoff[i];
  int je = rowoff[i + 1];
  float s = 0.f;
  for (int j = jb + q; j < je; j += 4) s += h2[csr[j]];
  s += __shfl_xor(s, 1);
  s += __shfl_xor(s, 2);
  if (q == 0) out[i] = s * invI[i] + b2[0];
}

extern "C" void kernel_launch(void* const* d_in, const int* in_sizes, int n_in,
                              void* d_out, int out_size, void* d_ws, size_t ws_size,
                              hipStream_t stream) {
  const float* x   = (const float*)d_in[0];
  const int*   src = (const int*)d_in[1];
  const int*   dst = (const int*)d_in[2];
  const float* W1  = (const float*)d_in[3];
  const float* b1  = (const float*)d_in[4];
  const float* W2  = (const float*)d_in[5];
  const float* b2  = (const float*)d_in[6];
  int N = in_sizes[0] / NF;
  int E = in_sizes[1];
  int NB = (N + 255) >> 8;             // <= 512

  int* cntO       = (int*)d_ws;                    // N
  int* bucketCnt  = cntO + (size_t)N;              // 512
  int* bucketBase = bucketCnt + 512;               // 512
  int* rowoff     = bucketBase + 512;              // N+1 (pad to N+8)
  int* csr        = rowoff + (size_t)N + 8;        // E
  int2* region    = (int2*)(csr + (size_t)E);      // NB*CAP int2
  float* invO     = (float*)(region + (size_t)NB * CAP);
  float* invI     = invO + N;
  float* h2       = invI + N;
  unsigned short* xw = (unsigned short*)(h2 + N);  // N*128 bf16
  float* out      = (float*)d_out;

  int NR = (N + HRANGE - 1) / HRANGE;
  int G  = ((N + 63) / 64) * 2;

  k_init<<<(N + 255) / 256, 256, 0, stream>>>(cntO, bucketCnt, rowoff, N, E);
  k_hist<<<NR * HB, 256, 0, stream>>>(src, cntO, N, E);
  k_binA<<<(E + EPB - 1) / EPB, 256, 0, stream>>>(src, dst, bucketCnt, region, E);
  k_bscan<<<1, 256, 0, stream>>>(bucketCnt, bucketBase, NB);
  k_binB<<<NB, 256, 0, stream>>>(region, bucketCnt, bucketBase, csr, rowoff, invI, N);
  k_invO<<<(N + 255) / 256, 256, 0, stream>>>(cntO, invO, N);
  k_gemm1<<<G, 256, 0, stream>>>(x, W1, xw, N);
  k_gather_proj<<<(N + 3) / 4, 256, 0, stream>>>(xw, rowoff, csr, invI, invO, b1, W2, h2, N);
  k_gather2<<<(N + 63) / 64, 256, 0, stream>>>(h2, rowoff, csr, invI, b2, out, N);
}

// Round 12
// 238.008 us; speedup vs baseline: 1.1369x; 1.1369x over previous
//
#include <hip/hip_runtime.h>
#include <hip/hip_bf16.h>

#define NF 128
#define EPB 4096      // edges per binA block (int2 staging, 32 KB)
#define EPB2 8192     // edges per binA2 block (int staging, 32 KB)
#define CAP 6144      // per-bucket region capacity (mean 4096, +32 sigma)

// ---------------- init ----------------
__global__ void k_init(int* __restrict__ bucketCnt, int* __restrict__ bucketCntS,
                       int* __restrict__ rowoff, int N, int E) {
  int i = blockIdx.x * 256 + threadIdx.x;
  if (i < 512) { bucketCnt[i] = 0; bucketCntS[i] = 0; }
  if (i == 0) rowoff[N] = E;
}

// ---------------- binA: LDS-staged binning of (dst,src) into 256-node buckets ----------------
__global__ __launch_bounds__(256) void k_binA(const int* __restrict__ src,
                                              const int* __restrict__ dst,
                                              int* __restrict__ bucketCnt,
                                              int2* __restrict__ region, int E) {
  __shared__ int cnt[512], scanv[512], cur[512], gb[512], s1[256];
  __shared__ int2 st[EPB];  // 32 KB
  int tid = threadIdx.x;
  int b0 = blockIdx.x * EPB;
  int n = E - b0; if (n > EPB) n = EPB;

  for (int k = tid; k < 512; k += 256) cnt[k] = 0;
  __syncthreads();
  for (int k = tid; k < n; k += 256) atomicAdd(&cnt[dst[b0 + k] >> 8], 1);
  __syncthreads();

  int c0 = cnt[2 * tid], c1 = cnt[2 * tid + 1];
  s1[tid] = c0 + c1;
  __syncthreads();
  for (int off = 1; off < 256; off <<= 1) {
    int v = (tid >= off) ? s1[tid - off] : 0;
    __syncthreads();
    s1[tid] += v;
    __syncthreads();
  }
  int excl = tid ? s1[tid - 1] : 0;
  scanv[2 * tid] = excl;
  scanv[2 * tid + 1] = excl + c0;
  cur[2 * tid] = excl;
  cur[2 * tid + 1] = excl + c0;
  gb[2 * tid]     = c0 ? atomicAdd(&bucketCnt[2 * tid], c0) : 0;
  gb[2 * tid + 1] = c1 ? atomicAdd(&bucketCnt[2 * tid + 1], c1) : 0;
  __syncthreads();

  for (int k = tid; k < n; k += 256) {
    int d = dst[b0 + k], s = src[b0 + k];
    int p = atomicAdd(&cur[d >> 8], 1);
    st[p] = make_int2(d, s);
  }
  __syncthreads();
  for (int k = tid; k < n; k += 256) {
    int2 e = st[k];
    int b = e.x >> 8;
    int gp = gb[b] + (k - scanv[b]);
    if (gp < CAP) region[(size_t)b * CAP + gp] = e;
  }
}

// ---------------- binA2: LDS-staged binning of bare src values (for out-degree) ----------------
__global__ __launch_bounds__(256) void k_binA2(const int* __restrict__ src,
                                               int* __restrict__ bucketCntS,
                                               int* __restrict__ regionS, int E) {
  __shared__ int cnt[512], scanv[512], cur[512], gb[512], s1[256];
  __shared__ int st[EPB2];  // 32 KB
  int tid = threadIdx.x;
  int b0 = blockIdx.x * EPB2;
  int n = E - b0; if (n > EPB2) n = EPB2;

  for (int k = tid; k < 512; k += 256) cnt[k] = 0;
  __syncthreads();
  for (int k = tid; k < n; k += 256) atomicAdd(&cnt[src[b0 + k] >> 8], 1);
  __syncthreads();

  int c0 = cnt[2 * tid], c1 = cnt[2 * tid + 1];
  s1[tid] = c0 + c1;
  __syncthreads();
  for (int off = 1; off < 256; off <<= 1) {
    int v = (tid >= off) ? s1[tid - off] : 0;
    __syncthreads();
    s1[tid] += v;
    __syncthreads();
  }
  int excl = tid ? s1[tid - 1] : 0;
  scanv[2 * tid] = excl;
  scanv[2 * tid + 1] = excl + c0;
  cur[2 * tid] = excl;
  cur[2 * tid + 1] = excl + c0;
  gb[2 * tid]     = c0 ? atomicAdd(&bucketCntS[2 * tid], c0) : 0;
  gb[2 * tid + 1] = c1 ? atomicAdd(&bucketCntS[2 * tid + 1], c1) : 0;
  __syncthreads();

  for (int k = tid; k < n; k += 256) {
    int s = src[b0 + k];
    int p = atomicAdd(&cur[s >> 8], 1);
    st[p] = s;
  }
  __syncthreads();
  for (int k = tid; k < n; k += 256) {
    int s = st[k];
    int b = s >> 8;
    int gp = gb[b] + (k - scanv[b]);
    if (gp < CAP) regionS[(size_t)b * CAP + gp] = s;
  }
}

// ---------------- bscan: exclusive scan of bucket counts -> csr bases ----------------
__global__ __launch_bounds__(256) void k_bscan(const int* __restrict__ bucketCnt,
                                               int* __restrict__ bucketBase, int NB) {
  __shared__ int s1[256];
  int tid = threadIdx.x;
  int c0 = (2 * tid < NB) ? bucketCnt[2 * tid] : 0;
  int c1 = (2 * tid + 1 < NB) ? bucketCnt[2 * tid + 1] : 0;
  s1[tid] = c0 + c1;
  __syncthreads();
  for (int off = 1; off < 256; off <<= 1) {
    int v = (tid >= off) ? s1[tid - off] : 0;
    __syncthreads();
    s1[tid] += v;
    __syncthreads();
  }
  int excl = tid ? s1[tid - 1] : 0;
  if (2 * tid < NB) bucketBase[2 * tid] = excl;
  if (2 * tid + 1 < NB) bucketBase[2 * tid + 1] = excl + c0;
}

// ---------------- binB: per-bucket counting sort -> csr + rowoff + invI ----------------
__global__ __launch_bounds__(256) void k_binB(const int2* __restrict__ region,
                                              const int* __restrict__ bucketCnt,
                                              const int* __restrict__ bucketBase,
                                              int* __restrict__ csr,
                                              int* __restrict__ rowoff,
                                              float* __restrict__ invI, int N) {
  __shared__ int hist[256], incl[256], cur[256];
  int tid = threadIdx.x;
  int b = blockIdx.x;
  int base = b << 8;
  int nN = N - base; if (nN > 256) nN = 256;
  int cntb = bucketCnt[b]; if (cntb > CAP) cntb = CAP;
  const int2* reg = region + (size_t)b * CAP;

  hist[tid] = 0;
  __syncthreads();
  for (int k = tid; k < cntb; k += 256) atomicAdd(&hist[reg[k].x - base], 1);
  __syncthreads();
  int h = hist[tid];
  incl[tid] = h;
  __syncthreads();
  for (int off = 1; off < 256; off <<= 1) {
    int v = (tid >= off) ? incl[tid - off] : 0;
    __syncthreads();
    incl[tid] += v;
    __syncthreads();
  }
  int startt = incl[tid] - h;  // exclusive
  int csrBase = bucketBase[b];
  if (tid < nN) {
    rowoff[base + tid] = csrBase + startt;
    invI[base + tid] = rsqrtf(fmaxf((float)h, 1.0f));
  }
  cur[tid] = startt;
  __syncthreads();
  for (int k = tid; k < cntb; k += 256) {
    int2 e = reg[k];
    int p = atomicAdd(&cur[e.x - base], 1);
    csr[csrBase + p] = e.y;  // store within small L2-resident window
  }
}

// ---------------- binB2: per-bucket src histogram -> invO ----------------
__global__ __launch_bounds__(256) void k_binB2(const int* __restrict__ regionS,
                                               const int* __restrict__ bucketCntS,
                                               float* __restrict__ invO, int N) {
  __shared__ int hist[256];
  int tid = threadIdx.x;
  int b = blockIdx.x;
  int base = b << 8;
  int cntb = bucketCntS[b]; if (cntb > CAP) cntb = CAP;
  const int* reg = regionS + (size_t)b * CAP;
  hist[tid] = 0;
  __syncthreads();
  for (int k = tid; k < cntb; k += 256) atomicAdd(&hist[reg[k] - base], 1);
  __syncthreads();
  if (base + tid < N) invO[base + tid] = rsqrtf(fmaxf((float)hist[tid], 1.0f));
}

// ---------------- layer-1 projection: xw = bf16( x @ W1 ), unscaled ----------------
__global__ __launch_bounds__(256) void k_gemm1(const float* __restrict__ x,
                                               const float* __restrict__ W1,
                                               unsigned short* __restrict__ xw, int N) {
  __shared__ float Wl[NF * 64];  // 32 KB
  int tid = threadIdx.x;
  int cb      = (blockIdx.x & 1) * 64;
  int rowbase = (blockIdx.x >> 1) * 64;

  for (int t = tid; t < NF * 16; t += 256) {
    int k = t >> 4, c4 = (t & 15) << 2;
    *(float4*)&Wl[k * 64 + c4] = *(const float4*)&W1[k * NF + cb + c4];
  }
  __syncthreads();

  int c4 = (tid & 15) << 2;
  int rg = tid >> 4;

  const float* xr[4];
#pragma unroll
  for (int r = 0; r < 4; ++r) {
    int row = rowbase + rg + r * 16;
    if (row >= N) row = N - 1;
    xr[r] = x + (size_t)row * NF;
  }

  float4 acc[4];
#pragma unroll
  for (int r = 0; r < 4; ++r) acc[r] = {0.f, 0.f, 0.f, 0.f};

  for (int k0 = 0; k0 < NF; k0 += 4) {
    float4 xv[4];
#pragma unroll
    for (int r = 0; r < 4; ++r) xv[r] = *(const float4*)&xr[r][k0];
#pragma unroll
    for (int j = 0; j < 4; ++j) {
      float4 w = *(float4*)&Wl[(k0 + j) * 64 + c4];
#pragma unroll
      for (int r = 0; r < 4; ++r) {
        float xs = j == 0 ? xv[r].x : j == 1 ? xv[r].y : j == 2 ? xv[r].z : xv[r].w;
        acc[r].x = fmaf(xs, w.x, acc[r].x);
        acc[r].y = fmaf(xs, w.y, acc[r].y);
        acc[r].z = fmaf(xs, w.z, acc[r].z);
        acc[r].w = fmaf(xs, w.w, acc[r].w);
      }
    }
  }

#pragma unroll
  for (int r = 0; r < 4; ++r) {
    int row = rowbase + rg + r * 16;
    if (row < N) {
      __hip_bfloat16 h0 = __float2bfloat16(acc[r].x);
      __hip_bfloat16 h1 = __float2bfloat16(acc[r].y);
      __hip_bfloat16 h2 = __float2bfloat16(acc[r].z);
      __hip_bfloat16 h3 = __float2bfloat16(acc[r].w);
      ushort4 o16;
      o16.x = *(unsigned short*)&h0;
      o16.y = *(unsigned short*)&h1;
      o16.z = *(unsigned short*)&h2;
      o16.w = *(unsigned short*)&h3;
      *(ushort4*)&xw[(size_t)row * NF + cb + c4] = o16;
    }
  }
}

// ---------------- fused gather + layer-2 projection (bf16 rows, invO per edge) ----------------
__global__ __launch_bounds__(256) void k_gather_proj(const unsigned short* __restrict__ xw,
                                                     const int* __restrict__ rowoff,
                                                     const int* __restrict__ csr,
                                                     const float* __restrict__ invI,
                                                     const float* __restrict__ invO,
                                                     const float* __restrict__ b1,
                                                     const float* __restrict__ W2,
                                                     float* __restrict__ h2, int N) {
  int i    = blockIdx.x * 4 + (threadIdx.x >> 6);
  int lane = threadIdx.x & 63;
  int half = lane >> 5;
  int sl   = lane & 31;
  if (i >= N) return;
  int jb = rowoff[i];
  int je = rowoff[i + 1];
  const uint2* xwq = (const uint2*)xw;  // 4 bf16 per uint2, 32 per row
  float a0 = 0.f, a1 = 0.f, a2 = 0.f, a3 = 0.f;

#define BF_FMA(v, o)                                                       \
  do {                                                                     \
    a0 = fmaf(__uint_as_float(((v).x & 0xffffu) << 16), (o), a0);          \
    a1 = fmaf(__uint_as_float((v).x & 0xffff0000u), (o), a1);              \
    a2 = fmaf(__uint_as_float(((v).y & 0xffffu) << 16), (o), a2);          \
    a3 = fmaf(__uint_as_float((v).y & 0xffff0000u), (o), a3);              \
  } while (0)

  int j = jb;
  for (; j + 8 <= je; j += 8) {
    int s0 = csr[j     + half];
    int s1 = csr[j + 2 + half];
    int s2 = csr[j + 4 + half];
    int s3 = csr[j + 6 + half];
    float o0 = invO[s0], o1 = invO[s1], o2 = invO[s2], o3 = invO[s3];
    uint2 v0 = xwq[(size_t)s0 * 32 + sl];
    uint2 v1 = xwq[(size_t)s1 * 32 + sl];
    uint2 v2 = xwq[(size_t)s2 * 32 + sl];
    uint2 v3 = xwq[(size_t)s3 * 32 + sl];
    BF_FMA(v0, o0); BF_FMA(v1, o1); BF_FMA(v2, o2); BF_FMA(v3, o3);
  }
  for (; j < je; j += 2) {
    int e = j + half;
    if (e < je) {
      int s = csr[e];
      float o = invO[s];
      uint2 v = xwq[(size_t)s * 32 + sl];
      BF_FMA(v, o);
    }
  }
#undef BF_FMA

  a0 += __shfl_xor(a0, 32);
  a1 += __shfl_xor(a1, 32);
  a2 += __shfl_xor(a2, 32);
  a3 += __shfl_xor(a3, 32);

  float inI = invI[i];
  int f = sl * 4;
  float4 bb = *(const float4*)&b1[f];
  float4 ww = *(const float4*)&W2[f];
  float u0 = fmaxf(fmaf(a0, inI, bb.x), 0.f);
  float u1 = fmaxf(fmaf(a1, inI, bb.y), 0.f);
  float u2 = fmaxf(fmaf(a2, inI, bb.z), 0.f);
  float u3 = fmaxf(fmaf(a3, inI, bb.w), 0.f);
  float p = u0 * ww.x + u1 * ww.y + u2 * ww.z + u3 * ww.w;
#pragma unroll
  for (int off = 16; off; off >>= 1) p += __shfl_xor(p, off);
  if (lane == 0) h2[i] = p * invO[i];
}

// ---------------- layer-2 gather + epilogue (4 lanes per node) ----------------
__global__ __launch_bounds__(256) void k_gather2(const float* __restrict__ h2,
                                                 const int* __restrict__ rowoff,
                                                 const int* __restrict__ csr,
                                                 const float* __restrict__ invI,
                                                 const float* __restrict__ b2,
                                                 float* __restrict__ out, int N) {
  int i = blockIdx.x * 64 + (threadIdx.x >> 2);
  int q = threadIdx.x & 3;
  if (i >= N) return;
  int jb = rowoff[i];
  int je = rowoff[i + 1];
  float s = 0.f;
  for (int j = jb + q; j < je; j += 4) s += h2[csr[j]];
  s += __shfl_xor(s, 1);
  s += __shfl_xor(s, 2);
  if (q == 0) out[i] = s * invI[i] + b2[0];
}

extern "C" void kernel_launch(void* const* d_in, const int* in_sizes, int n_in,
                              void* d_out, int out_size, void* d_ws, size_t ws_size,
                              hipStream_t stream) {
  const float* x   = (const float*)d_in[0];
  const int*   src = (const int*)d_in[1];
  const int*   dst = (const int*)d_in[2];
  const float* W1  = (const float*)d_in[3];
  const float* b1  = (const float*)d_in[4];
  const float* W2  = (const float*)d_in[5];
  const float* b2  = (const float*)d_in[6];
  int N = in_sizes[0] / NF;
  int E = in_sizes[1];
  int NB = (N + 255) >> 8;             // <= 512

  int* bucketCnt  = (int*)d_ws;                    // 512
  int* bucketCntS = bucketCnt + 512;               // 512
  int* bucketBase = bucketCntS + 512;              // 512
  int* rowoff     = bucketBase + 512;              // N+1 (pad to N+8)
  int* csr        = rowoff + (size_t)N + 8;        // E
  int2* region    = (int2*)(csr + (size_t)E);      // NB*CAP int2
  int* regionS    = (int*)(region + (size_t)NB * CAP);  // NB*CAP int
  float* invO     = (float*)(regionS + (size_t)NB * CAP);
  float* invI     = invO + N;
  float* h2       = invI + N;
  unsigned short* xw = (unsigned short*)(h2 + N);  // N*128 bf16
  float* out      = (float*)d_out;

  int G = ((N + 63) / 64) * 2;

  k_init<<<(N + 255) / 256, 256, 0, stream>>>(bucketCnt, bucketCntS, rowoff, N, E);
  k_binA<<<(E + EPB - 1) / EPB, 256, 0, stream>>>(src, dst, bucketCnt, region, E);
  k_binA2<<<(E + EPB2 - 1) / EPB2, 256, 0, stream>>>(src, bucketCntS, regionS, E);
  k_bscan<<<1, 256, 0, stream>>>(bucketCnt, bucketBase, NB);
  k_binB<<<NB, 256, 0, stream>>>(region, bucketCnt, bucketBase, csr, rowoff, invI, N);
  k_binB2<<<NB, 256, 0, stream>>>(regionS, bucketCntS, invO, N);
  k_gemm1<<<G, 256, 0, stream>>>(x, W1, xw, N);
  k_gather_proj<<<(N + 3) / 4, 256, 0, stream>>>(xw, rowoff, csr, invI, invO, b1, W2, h2, N);
  k_gather2<<<(N + 63) / 64, 256, 0, stream>>>(h2, rowoff, csr, invI, b2, out, N);
}

// Round 13
// 214.282 us; speedup vs baseline: 1.2627x; 1.1107x over previous
//
#include <hip/hip_runtime.h>
#include <hip/hip_bf16.h>

#define NF 128
#define EPB 2048      // edges per binA role block (int2 staging, 16 KB + 9 KB ctl)
#define EPB2 4096     // edges per binA2 role block (int staging, 16 KB + 9 KB ctl)
#define CAP 6144      // per-bucket region capacity (mean 4096, +32 sigma)

// ---------------- init (1 block) ----------------
__global__ void k_init(int* __restrict__ bucketCnt, int* __restrict__ bucketCntS,
                       int* __restrict__ rowoff, int N, int E) {
  int i = threadIdx.x;
  for (int k = i; k < 512; k += 256) { bucketCnt[k] = 0; bucketCntS[k] = 0; }
  if (i == 0) rowoff[N] = E;
}

// ---------------- front: binA | binA2 | gemm1 heterogeneous roles ----------------
__global__ __launch_bounds__(256) void k_front(const float* __restrict__ x,
                                               const int* __restrict__ src,
                                               const int* __restrict__ dst,
                                               const float* __restrict__ W1,
                                               int* __restrict__ bucketCnt,
                                               int* __restrict__ bucketCntS,
                                               int2* __restrict__ region,
                                               int* __restrict__ regionS,
                                               unsigned short* __restrict__ xw,
                                               int N, int E, int B1, int B2) {
  __shared__ __align__(16) char smem_raw[32768];
  int tid = threadIdx.x;
  int b = blockIdx.x;

  if (b < B1) {
    // ---- binA role: bin (dst,src) pairs into 256-node buckets ----
    int* cnt   = (int*)smem_raw;
    int* scanv = cnt + 512;
    int* cur   = scanv + 512;
    int* gb    = cur + 512;
    int* s1    = gb + 512;
    int2* st   = (int2*)(s1 + 256);  // EPB int2 = 16 KB
    int b0 = b * EPB;
    int n = E - b0; if (n > EPB) n = EPB;

    for (int k = tid; k < 512; k += 256) cnt[k] = 0;
    __syncthreads();
    for (int k = tid; k < n; k += 256) atomicAdd(&cnt[dst[b0 + k] >> 8], 1);
    __syncthreads();

    int c0 = cnt[2 * tid], c1 = cnt[2 * tid + 1];
    s1[tid] = c0 + c1;
    __syncthreads();
    for (int off = 1; off < 256; off <<= 1) {
      int v = (tid >= off) ? s1[tid - off] : 0;
      __syncthreads();
      s1[tid] += v;
      __syncthreads();
    }
    int excl = tid ? s1[tid - 1] : 0;
    scanv[2 * tid] = excl;
    scanv[2 * tid + 1] = excl + c0;
    cur[2 * tid] = excl;
    cur[2 * tid + 1] = excl + c0;
    gb[2 * tid]     = c0 ? atomicAdd(&bucketCnt[2 * tid], c0) : 0;
    gb[2 * tid + 1] = c1 ? atomicAdd(&bucketCnt[2 * tid + 1], c1) : 0;
    __syncthreads();

    for (int k = tid; k < n; k += 256) {
      int d = dst[b0 + k], s = src[b0 + k];
      int p = atomicAdd(&cur[d >> 8], 1);
      st[p] = make_int2(d, s);
    }
    __syncthreads();
    for (int k = tid; k < n; k += 256) {
      int2 e = st[k];
      int bk = e.x >> 8;
      int gp = gb[bk] + (k - scanv[bk]);
      if (gp < CAP) region[(size_t)bk * CAP + gp] = e;
    }
    return;
  }

  if (b < B1 + B2) {
    // ---- binA2 role: bin bare src values (out-degree) ----
    int* cnt   = (int*)smem_raw;
    int* scanv = cnt + 512;
    int* cur   = scanv + 512;
    int* gb    = cur + 512;
    int* s1    = gb + 512;
    int* st    = s1 + 256;  // EPB2 ints = 16 KB
    int b0 = (b - B1) * EPB2;
    int n = E - b0; if (n > EPB2) n = EPB2;

    for (int k = tid; k < 512; k += 256) cnt[k] = 0;
    __syncthreads();
    for (int k = tid; k < n; k += 256) atomicAdd(&cnt[src[b0 + k] >> 8], 1);
    __syncthreads();

    int c0 = cnt[2 * tid], c1 = cnt[2 * tid + 1];
    s1[tid] = c0 + c1;
    __syncthreads();
    for (int off = 1; off < 256; off <<= 1) {
      int v = (tid >= off) ? s1[tid - off] : 0;
      __syncthreads();
      s1[tid] += v;
      __syncthreads();
    }
    int excl = tid ? s1[tid - 1] : 0;
    scanv[2 * tid] = excl;
    scanv[2 * tid + 1] = excl + c0;
    cur[2 * tid] = excl;
    cur[2 * tid + 1] = excl + c0;
    gb[2 * tid]     = c0 ? atomicAdd(&bucketCntS[2 * tid], c0) : 0;
    gb[2 * tid + 1] = c1 ? atomicAdd(&bucketCntS[2 * tid + 1], c1) : 0;
    __syncthreads();

    for (int k = tid; k < n; k += 256) {
      int s = src[b0 + k];
      int p = atomicAdd(&cur[s >> 8], 1);
      st[p] = s;
    }
    __syncthreads();
    for (int k = tid; k < n; k += 256) {
      int s = st[k];
      int bk = s >> 8;
      int gp = gb[bk] + (k - scanv[bk]);
      if (gp < CAP) regionS[(size_t)bk * CAP + gp] = s;
    }
    return;
  }

  // ---- gemm role: xw = bf16( x @ W1 ), unscaled ----
  float* Wl = (float*)smem_raw;  // [128][64], 32 KB
  int idx = b - B1 - B2;
  int cb      = (idx & 1) * 64;
  int rowbase = (idx >> 1) * 64;

  for (int t = tid; t < NF * 16; t += 256) {
    int k = t >> 4, c4 = (t & 15) << 2;
    *(float4*)&Wl[k * 64 + c4] = *(const float4*)&W1[k * NF + cb + c4];
  }
  __syncthreads();

  int c4 = (tid & 15) << 2;
  int rg = tid >> 4;

  const float* xr[4];
#pragma unroll
  for (int r = 0; r < 4; ++r) {
    int row = rowbase + rg + r * 16;
    if (row >= N) row = N - 1;
    xr[r] = x + (size_t)row * NF;
  }

  float4 acc[4];
#pragma unroll
  for (int r = 0; r < 4; ++r) acc[r] = {0.f, 0.f, 0.f, 0.f};

  for (int k0 = 0; k0 < NF; k0 += 4) {
    float4 xv[4];
#pragma unroll
    for (int r = 0; r < 4; ++r) xv[r] = *(const float4*)&xr[r][k0];
#pragma unroll
    for (int j = 0; j < 4; ++j) {
      float4 w = *(float4*)&Wl[(k0 + j) * 64 + c4];
#pragma unroll
      for (int r = 0; r < 4; ++r) {
        float xs = j == 0 ? xv[r].x : j == 1 ? xv[r].y : j == 2 ? xv[r].z : xv[r].w;
        acc[r].x = fmaf(xs, w.x, acc[r].x);
        acc[r].y = fmaf(xs, w.y, acc[r].y);
        acc[r].z = fmaf(xs, w.z, acc[r].z);
        acc[r].w = fmaf(xs, w.w, acc[r].w);
      }
    }
  }

#pragma unroll
  for (int r = 0; r < 4; ++r) {
    int row = rowbase + rg + r * 16;
    if (row < N) {
      __hip_bfloat16 h0 = __float2bfloat16(acc[r].x);
      __hip_bfloat16 h1 = __float2bfloat16(acc[r].y);
      __hip_bfloat16 h2 = __float2bfloat16(acc[r].z);
      __hip_bfloat16 h3 = __float2bfloat16(acc[r].w);
      ushort4 o16;
      o16.x = *(unsigned short*)&h0;
      o16.y = *(unsigned short*)&h1;
      o16.z = *(unsigned short*)&h2;
      o16.w = *(unsigned short*)&h3;
      *(ushort4*)&xw[(size_t)row * NF + cb + c4] = o16;
    }
  }
}

// ---------------- back: binB (inline bucket scan) | binB2 ----------------
__global__ __launch_bounds__(256) void k_back(const int2* __restrict__ region,
                                              const int* __restrict__ bucketCnt,
                                              const int* __restrict__ regionS,
                                              const int* __restrict__ bucketCntS,
                                              int* __restrict__ csr,
                                              int* __restrict__ rowoff,
                                              float* __restrict__ invI,
                                              float* __restrict__ invO,
                                              int N, int NB) {
  __shared__ int s1[256], hist[256], incl[256], cur[256];
  int tid = threadIdx.x;
  int blk = blockIdx.x;

  if (blk < NB) {
    // ---- binB role: counting sort -> csr + rowoff + invI ----
    int b = blk;
    // inline exclusive scan of bucketCnt to get csrBase for this bucket
    int c0 = (2 * tid < NB) ? bucketCnt[2 * tid] : 0;
    int c1 = (2 * tid + 1 < NB) ? bucketCnt[2 * tid + 1] : 0;
    s1[tid] = c0 + c1;
    __syncthreads();
    for (int off = 1; off < 256; off <<= 1) {
      int v = (tid >= off) ? s1[tid - off] : 0;
      __syncthreads();
      s1[tid] += v;
      __syncthreads();
    }
    int t = b >> 1;
    int csrBase = t ? s1[t - 1] : 0;
    if (b & 1) csrBase += bucketCnt[b & ~1];

    int base = b << 8;
    int nN = N - base; if (nN > 256) nN = 256;
    int cntb = bucketCnt[b]; if (cntb > CAP) cntb = CAP;
    const int2* reg = region + (size_t)b * CAP;

    hist[tid] = 0;
    __syncthreads();
    for (int k = tid; k < cntb; k += 256) atomicAdd(&hist[reg[k].x - base], 1);
    __syncthreads();
    int h = hist[tid];
    incl[tid] = h;
    __syncthreads();
    for (int off = 1; off < 256; off <<= 1) {
      int v = (tid >= off) ? incl[tid - off] : 0;
      __syncthreads();
      incl[tid] += v;
      __syncthreads();
    }
    int startt = incl[tid] - h;  // exclusive
    if (tid < nN) {
      rowoff[base + tid] = csrBase + startt;
      invI[base + tid] = rsqrtf(fmaxf((float)h, 1.0f));
    }
    cur[tid] = startt;
    __syncthreads();
    for (int k = tid; k < cntb; k += 256) {
      int2 e = reg[k];
      int p = atomicAdd(&cur[e.x - base], 1);
      csr[csrBase + p] = e.y;
    }
    return;
  }

  // ---- binB2 role: src histogram -> invO ----
  int b = blk - NB;
  int base = b << 8;
  int cntb = bucketCntS[b]; if (cntb > CAP) cntb = CAP;
  const int* reg = regionS + (size_t)b * CAP;
  hist[tid] = 0;
  __syncthreads();
  for (int k = tid; k < cntb; k += 256) atomicAdd(&hist[reg[k] - base], 1);
  __syncthreads();
  if (base + tid < N) invO[base + tid] = rsqrtf(fmaxf((float)hist[tid], 1.0f));
}

// ---------------- fused gather + layer-2 projection (uint4 loads) ----------------
// 16 lanes cover a 256 B row; 4 edges per wave-load round; 8 f32 acc per lane.
__global__ __launch_bounds__(256) void k_gather_proj(const unsigned short* __restrict__ xw,
                                                     const int* __restrict__ rowoff,
                                                     const int* __restrict__ csr,
                                                     const float* __restrict__ invI,
                                                     const float* __restrict__ invO,
                                                     const float* __restrict__ b1,
                                                     const float* __restrict__ W2,
                                                     float* __restrict__ h2, int N) {
  int i    = blockIdx.x * 4 + (threadIdx.x >> 6);
  int lane = threadIdx.x & 63;
  int grp  = lane >> 4;   // 0..3
  int sl   = lane & 15;
  if (i >= N) return;
  int jb = rowoff[i];
  int je = rowoff[i + 1];
  const uint4* xwq = (const uint4*)xw;  // 16 uint4 per row
  float a0 = 0.f, a1 = 0.f, a2 = 0.f, a3 = 0.f;
  float a4 = 0.f, a5 = 0.f, a6 = 0.f, a7 = 0.f;

#define ACC8(v, o)                                                         \
  do {                                                                     \
    a0 = fmaf(__uint_as_float(((v).x & 0xffffu) << 16), (o), a0);          \
    a1 = fmaf(__uint_as_float((v).x & 0xffff0000u), (o), a1);              \
    a2 = fmaf(__uint_as_float(((v).y & 0xffffu) << 16), (o), a2);          \
    a3 = fmaf(__uint_as_float((v).y & 0xffff0000u), (o), a3);              \
    a4 = fmaf(__uint_as_float(((v).z & 0xffffu) << 16), (o), a4);          \
    a5 = fmaf(__uint_as_float((v).z & 0xffff0000u), (o), a5);              \
    a6 = fmaf(__uint_as_float(((v).w & 0xffffu) << 16), (o), a6);          \
    a7 = fmaf(__uint_as_float((v).w & 0xffff0000u), (o), a7);              \
  } while (0)

  int j = jb;
  for (; j + 8 <= je; j += 8) {
    int s0 = csr[j + grp];
    int s1 = csr[j + 4 + grp];
    float o0 = invO[s0], o1 = invO[s1];
    uint4 v0 = xwq[(size_t)s0 * 16 + sl];
    uint4 v1 = xwq[(size_t)s1 * 16 + sl];
    ACC8(v0, o0);
    ACC8(v1, o1);
  }
  for (; j < je; j += 4) {
    int e = j + grp;
    if (e < je) {
      int s = csr[e];
      float o = invO[s];
      uint4 v = xwq[(size_t)s * 16 + sl];
      ACC8(v, o);
    }
  }
#undef ACC8

  // reduce across the 4 groups (every lane ends with the full row sum)
  a0 += __shfl_xor(a0, 16); a0 += __shfl_xor(a0, 32);
  a1 += __shfl_xor(a1, 16); a1 += __shfl_xor(a1, 32);
  a2 += __shfl_xor(a2, 16); a2 += __shfl_xor(a2, 32);
  a3 += __shfl_xor(a3, 16); a3 += __shfl_xor(a3, 32);
  a4 += __shfl_xor(a4, 16); a4 += __shfl_xor(a4, 32);
  a5 += __shfl_xor(a5, 16); a5 += __shfl_xor(a5, 32);
  a6 += __shfl_xor(a6, 16); a6 += __shfl_xor(a6, 32);
  a7 += __shfl_xor(a7, 16); a7 += __shfl_xor(a7, 32);

  float inI = invI[i];
  int f = sl * 8;
  float4 bl = *(const float4*)&b1[f];
  float4 bh = *(const float4*)&b1[f + 4];
  float4 wl = *(const float4*)&W2[f];
  float4 wh = *(const float4*)&W2[f + 4];
  float p = fmaxf(fmaf(a0, inI, bl.x), 0.f) * wl.x
          + fmaxf(fmaf(a1, inI, bl.y), 0.f) * wl.y
          + fmaxf(fmaf(a2, inI, bl.z), 0.f) * wl.z
          + fmaxf(fmaf(a3, inI, bl.w), 0.f) * wl.w
          + fmaxf(fmaf(a4, inI, bh.x), 0.f) * wh.x
          + fmaxf(fmaf(a5, inI, bh.y), 0.f) * wh.y
          + fmaxf(fmaf(a6, inI, bh.z), 0.f) * wh.z
          + fmaxf(fmaf(a7, inI, bh.w), 0.f) * wh.w;
#pragma unroll
  for (int off = 8; off; off >>= 1) p += __shfl_xor(p, off);
  if (lane == 0) h2[i] = p * invO[i];
}

// ---------------- layer-2 gather + epilogue (4 lanes per node) ----------------
__global__ __launch_bounds__(256) void k_gather2(const float* __restrict__ h2,
                                                 const int* __restrict__ rowoff,
                                                 const int* __restrict__ csr,
                                                 const float* __restrict__ invI,
                                                 const float* __restrict__ b2,
                                                 float* __restrict__ out, int N) {
  int i = blockIdx.x * 64 + (threadIdx.x >> 2);
  int q = threadIdx.x & 3;
  if (i >= N) return;
  int jb = rowoff[i];
  int je = rowoff[i + 1];
  float s = 0.f;
  for (int j = jb + q; j < je; j += 4) s += h2[csr[j]];
  s += __shfl_xor(s, 1);
  s += __shfl_xor(s, 2);
  if (q == 0) out[i] = s * invI[i] + b2[0];
}

extern "C" void kernel_launch(void* const* d_in, const int* in_sizes, int n_in,
                              void* d_out, int out_size, void* d_ws, size_t ws_size,
                              hipStream_t stream) {
  const float* x   = (const float*)d_in[0];
  const int*   src = (const int*)d_in[1];
  const int*   dst = (const int*)d_in[2];
  const float* W1  = (const float*)d_in[3];
  const float* b1  = (const float*)d_in[4];
  const float* W2  = (const float*)d_in[5];
  const float* b2  = (const float*)d_in[6];
  int N = in_sizes[0] / NF;
  int E = in_sizes[1];
  int NB = (N + 255) >> 8;             // <= 512

  int* bucketCnt  = (int*)d_ws;                    // 512
  int* bucketCntS = bucketCnt + 512;               // 512
  int* rowoff     = bucketCntS + 512;              // N+1 (pad to N+8)
  int* csr        = rowoff + (size_t)N + 8;        // E
  int2* region    = (int2*)(csr + (size_t)E);      // NB*CAP int2
  int* regionS    = (int*)(region + (size_t)NB * CAP);  // NB*CAP int
  float* invO     = (float*)(regionS + (size_t)NB * CAP);
  float* invI     = invO + N;
  float* h2       = invI + N;
  unsigned short* xw = (unsigned short*)(h2 + N);  // N*128 bf16
  float* out      = (float*)d_out;

  int B1 = (E + EPB - 1) / EPB;        // binA role blocks
  int B2 = (E + EPB2 - 1) / EPB2;      // binA2 role blocks
  int G  = ((N + 63) / 64) * 2;        // gemm role blocks

  k_init<<<1, 256, 0, stream>>>(bucketCnt, bucketCntS, rowoff, N, E);
  k_front<<<B1 + B2 + G, 256, 0, stream>>>(x, src, dst, W1, bucketCnt, bucketCntS,
                                           region, regionS, xw, N, E, B1, B2);
  k_back<<<2 * NB, 256, 0, stream>>>(region, bucketCnt, regionS, bucketCntS,
                                     csr, rowoff, invI, invO, N, NB);
  k_gather_proj<<<(N + 3) / 4, 256, 0, stream>>>(xw, rowoff, csr, invI, invO, b1, W2, h2, N);
  k_gather2<<<(N + 63) / 64, 256, 0, stream>>>(h2, rowoff, csr, invI, b2, out, N);
}

// Round 14
// 206.366 us; speedup vs baseline: 1.3112x; 1.0384x over previous
//
#include <hip/hip_runtime.h>
#include <hip/hip_bf16.h>

#define NF 128
#define EPB 4096      // edges per binA role block (int2 staging, 32 KB)
#define EPB2 8192     // edges per binA2 role block (int staging, 32 KB)
#define CAP 6144      // per-bucket region capacity (mean 4096, +32 sigma)

// ---------------- init (1 block) ----------------
__global__ void k_init(int* __restrict__ bucketCnt, int* __restrict__ bucketCntS,
                       int* __restrict__ rowoff, int N, int E) {
  int i = threadIdx.x;
  for (int k = i; k < 512; k += 256) { bucketCnt[k] = 0; bucketCntS[k] = 0; }
  if (i == 0) rowoff[N] = E;
}

// ---------------- frontA: binA | binA2 (both memory-bound binning) ----------------
__global__ __launch_bounds__(256) void k_frontA(const int* __restrict__ src,
                                                const int* __restrict__ dst,
                                                int* __restrict__ bucketCnt,
                                                int* __restrict__ bucketCntS,
                                                int2* __restrict__ region,
                                                int* __restrict__ regionS,
                                                int E, int B1) {
  __shared__ __align__(16) char smem_raw[42240];  // 9216 ctl + 32768 staging
  int* cnt   = (int*)smem_raw;
  int* scanv = cnt + 512;
  int* cur   = scanv + 512;
  int* gb    = cur + 512;
  int* s1    = gb + 512;
  void* stv  = (void*)(smem_raw + 9216 + 256);  // 16B-aligned staging
  int tid = threadIdx.x;
  int b = blockIdx.x;

  if (b < B1) {
    // ---- binA role: bin (dst,src) pairs into 256-node buckets ----
    int2* st = (int2*)stv;
    int b0 = b * EPB;
    int n = E - b0; if (n > EPB) n = EPB;

    for (int k = tid; k < 512; k += 256) cnt[k] = 0;
    __syncthreads();
    for (int k = tid; k < n; k += 256) atomicAdd(&cnt[dst[b0 + k] >> 8], 1);
    __syncthreads();

    int c0 = cnt[2 * tid], c1 = cnt[2 * tid + 1];
    s1[tid] = c0 + c1;
    __syncthreads();
    for (int off = 1; off < 256; off <<= 1) {
      int v = (tid >= off) ? s1[tid - off] : 0;
      __syncthreads();
      s1[tid] += v;
      __syncthreads();
    }
    int excl = tid ? s1[tid - 1] : 0;
    scanv[2 * tid] = excl;
    scanv[2 * tid + 1] = excl + c0;
    cur[2 * tid] = excl;
    cur[2 * tid + 1] = excl + c0;
    gb[2 * tid]     = c0 ? atomicAdd(&bucketCnt[2 * tid], c0) : 0;
    gb[2 * tid + 1] = c1 ? atomicAdd(&bucketCnt[2 * tid + 1], c1) : 0;
    __syncthreads();

    for (int k = tid; k < n; k += 256) {
      int d = dst[b0 + k], s = src[b0 + k];
      int p = atomicAdd(&cur[d >> 8], 1);
      st[p] = make_int2(d, s);
    }
    __syncthreads();
    for (int k = tid; k < n; k += 256) {
      int2 e = st[k];
      int bk = e.x >> 8;
      int gp = gb[bk] + (k - scanv[bk]);
      if (gp < CAP) region[(size_t)bk * CAP + gp] = e;
    }
    return;
  }

  // ---- binA2 role: bin bare src values (out-degree) ----
  int* st = (int*)stv;
  int b0 = (b - B1) * EPB2;
  int n = E - b0; if (n > EPB2) n = EPB2;

  for (int k = tid; k < 512; k += 256) cnt[k] = 0;
  __syncthreads();
  for (int k = tid; k < n; k += 256) atomicAdd(&cnt[src[b0 + k] >> 8], 1);
  __syncthreads();

  int c0 = cnt[2 * tid], c1 = cnt[2 * tid + 1];
  s1[tid] = c0 + c1;
  __syncthreads();
  for (int off = 1; off < 256; off <<= 1) {
    int v = (tid >= off) ? s1[tid - off] : 0;
    __syncthreads();
    s1[tid] += v;
    __syncthreads();
  }
  int excl = tid ? s1[tid - 1] : 0;
  scanv[2 * tid] = excl;
  scanv[2 * tid + 1] = excl + c0;
  cur[2 * tid] = excl;
  cur[2 * tid + 1] = excl + c0;
  gb[2 * tid]     = c0 ? atomicAdd(&bucketCntS[2 * tid], c0) : 0;
  gb[2 * tid + 1] = c1 ? atomicAdd(&bucketCntS[2 * tid + 1], c1) : 0;
  __syncthreads();

  for (int k = tid; k < n; k += 256) {
    int s = src[b0 + k];
    int p = atomicAdd(&cur[s >> 8], 1);
    st[p] = s;
  }
  __syncthreads();
  for (int k = tid; k < n; k += 256) {
    int s = st[k];
    int bk = s >> 8;
    int gp = gb[bk] + (k - scanv[bk]);
    if (gp < CAP) regionS[(size_t)bk * CAP + gp] = s;
  }
}

// ---------------- mid: binB | binB2 | gemm1 (gemm-dominated, binB hides under it) ----------------
__global__ __launch_bounds__(256) void k_mid(const float* __restrict__ x,
                                             const float* __restrict__ W1,
                                             const int2* __restrict__ region,
                                             const int* __restrict__ bucketCnt,
                                             const int* __restrict__ regionS,
                                             const int* __restrict__ bucketCntS,
                                             int* __restrict__ csr,
                                             int* __restrict__ rowoff,
                                             float* __restrict__ invI,
                                             float* __restrict__ invO,
                                             unsigned short* __restrict__ xw,
                                             int N, int NB) {
  __shared__ __align__(16) char smem_raw[32768];
  int tid = threadIdx.x;
  int blk = blockIdx.x;

  if (blk < NB) {
    // ---- binB role: counting sort -> csr + rowoff + invI ----
    int* s1   = (int*)smem_raw;
    int* hist = s1 + 256;
    int* incl = hist + 256;
    int* cur  = incl + 256;
    int b = blk;
    int c0 = (2 * tid < NB) ? bucketCnt[2 * tid] : 0;
    int c1 = (2 * tid + 1 < NB) ? bucketCnt[2 * tid + 1] : 0;
    s1[tid] = c0 + c1;
    __syncthreads();
    for (int off = 1; off < 256; off <<= 1) {
      int v = (tid >= off) ? s1[tid - off] : 0;
      __syncthreads();
      s1[tid] += v;
      __syncthreads();
    }
    int t = b >> 1;
    int csrBase = t ? s1[t - 1] : 0;
    if (b & 1) csrBase += bucketCnt[b & ~1];

    int base = b << 8;
    int nN = N - base; if (nN > 256) nN = 256;
    int cntb = bucketCnt[b]; if (cntb > CAP) cntb = CAP;
    const int2* reg = region + (size_t)b * CAP;

    hist[tid] = 0;
    __syncthreads();
    for (int k = tid; k < cntb; k += 256) atomicAdd(&hist[reg[k].x - base], 1);
    __syncthreads();
    int h = hist[tid];
    incl[tid] = h;
    __syncthreads();
    for (int off = 1; off < 256; off <<= 1) {
      int v = (tid >= off) ? incl[tid - off] : 0;
      __syncthreads();
      incl[tid] += v;
      __syncthreads();
    }
    int startt = incl[tid] - h;  // exclusive
    if (tid < nN) {
      rowoff[base + tid] = csrBase + startt;
      invI[base + tid] = rsqrtf(fmaxf((float)h, 1.0f));
    }
    cur[tid] = startt;
    __syncthreads();
    for (int k = tid; k < cntb; k += 256) {
      int2 e = reg[k];
      int p = atomicAdd(&cur[e.x - base], 1);
      csr[csrBase + p] = e.y;
    }
    return;
  }

  if (blk < 2 * NB) {
    // ---- binB2 role: src histogram -> invO ----
    int* hist = (int*)smem_raw;
    int b = blk - NB;
    int base = b << 8;
    int cntb = bucketCntS[b]; if (cntb > CAP) cntb = CAP;
    const int* reg = regionS + (size_t)b * CAP;
    hist[tid] = 0;
    __syncthreads();
    for (int k = tid; k < cntb; k += 256) atomicAdd(&hist[reg[k] - base], 1);
    __syncthreads();
    if (base + tid < N) invO[base + tid] = rsqrtf(fmaxf((float)hist[tid], 1.0f));
    return;
  }

  // ---- gemm role: xw = bf16( x @ W1 ), unscaled ----
  float* Wl = (float*)smem_raw;  // [128][64], 32 KB
  int idx = blk - 2 * NB;
  int cb      = (idx & 1) * 64;
  int rowbase = (idx >> 1) * 64;

  for (int t = tid; t < NF * 16; t += 256) {
    int k = t >> 4, c4 = (t & 15) << 2;
    *(float4*)&Wl[k * 64 + c4] = *(const float4*)&W1[k * NF + cb + c4];
  }
  __syncthreads();

  int c4 = (tid & 15) << 2;
  int rg = tid >> 4;

  const float* xr[4];
#pragma unroll
  for (int r = 0; r < 4; ++r) {
    int row = rowbase + rg + r * 16;
    if (row >= N) row = N - 1;
    xr[r] = x + (size_t)row * NF;
  }

  float4 acc[4];
#pragma unroll
  for (int r = 0; r < 4; ++r) acc[r] = {0.f, 0.f, 0.f, 0.f};

  for (int k0 = 0; k0 < NF; k0 += 4) {
    float4 xv[4];
#pragma unroll
    for (int r = 0; r < 4; ++r) xv[r] = *(const float4*)&xr[r][k0];
#pragma unroll
    for (int j = 0; j < 4; ++j) {
      float4 w = *(float4*)&Wl[(k0 + j) * 64 + c4];
#pragma unroll
      for (int r = 0; r < 4; ++r) {
        float xs = j == 0 ? xv[r].x : j == 1 ? xv[r].y : j == 2 ? xv[r].z : xv[r].w;
        acc[r].x = fmaf(xs, w.x, acc[r].x);
        acc[r].y = fmaf(xs, w.y, acc[r].y);
        acc[r].z = fmaf(xs, w.z, acc[r].z);
        acc[r].w = fmaf(xs, w.w, acc[r].w);
      }
    }
  }

#pragma unroll
  for (int r = 0; r < 4; ++r) {
    int row = rowbase + rg + r * 16;
    if (row < N) {
      __hip_bfloat16 h0 = __float2bfloat16(acc[r].x);
      __hip_bfloat16 h1 = __float2bfloat16(acc[r].y);
      __hip_bfloat16 h2 = __float2bfloat16(acc[r].z);
      __hip_bfloat16 h3 = __float2bfloat16(acc[r].w);
      ushort4 o16;
      o16.x = *(unsigned short*)&h0;
      o16.y = *(unsigned short*)&h1;
      o16.z = *(unsigned short*)&h2;
      o16.w = *(unsigned short*)&h3;
      *(ushort4*)&xw[(size_t)row * NF + cb + c4] = o16;
    }
  }
}

// ---------------- fused gather + layer-2 projection (uint4 loads) ----------------
__global__ __launch_bounds__(256) void k_gather_proj(const unsigned short* __restrict__ xw,
                                                     const int* __restrict__ rowoff,
                                                     const int* __restrict__ csr,
                                                     const float* __restrict__ invI,
                                                     const float* __restrict__ invO,
                                                     const float* __restrict__ b1,
                                                     const float* __restrict__ W2,
                                                     float* __restrict__ h2, int N) {
  int i    = blockIdx.x * 4 + (threadIdx.x >> 6);
  int lane = threadIdx.x & 63;
  int grp  = lane >> 4;   // 0..3
  int sl   = lane & 15;
  if (i >= N) return;
  int jb = rowoff[i];
  int je = rowoff[i + 1];
  const uint4* xwq = (const uint4*)xw;  // 16 uint4 per row
  float a0 = 0.f, a1 = 0.f, a2 = 0.f, a3 = 0.f;
  float a4 = 0.f, a5 = 0.f, a6 = 0.f, a7 = 0.f;

#define ACC8(v, o)                                                         \
  do {                                                                     \
    a0 = fmaf(__uint_as_float(((v).x & 0xffffu) << 16), (o), a0);          \
    a1 = fmaf(__uint_as_float((v).x & 0xffff0000u), (o), a1);              \
    a2 = fmaf(__uint_as_float(((v).y & 0xffffu) << 16), (o), a2);          \
    a3 = fmaf(__uint_as_float((v).y & 0xffff0000u), (o), a3);              \
    a4 = fmaf(__uint_as_float(((v).z & 0xffffu) << 16), (o), a4);          \
    a5 = fmaf(__uint_as_float((v).z & 0xffff0000u), (o), a5);              \
    a6 = fmaf(__uint_as_float(((v).w & 0xffffu) << 16), (o), a6);          \
    a7 = fmaf(__uint_as_float((v).w & 0xffff0000u), (o), a7);              \
  } while (0)

  int j = jb;
  for (; j + 8 <= je; j += 8) {
    int s0 = csr[j + grp];
    int s1 = csr[j + 4 + grp];
    float o0 = invO[s0], o1 = invO[s1];
    uint4 v0 = xwq[(size_t)s0 * 16 + sl];
    uint4 v1 = xwq[(size_t)s1 * 16 + sl];
    ACC8(v0, o0);
    ACC8(v1, o1);
  }
  for (; j < je; j += 4) {
    int e = j + grp;
    if (e < je) {
      int s = csr[e];
      float o = invO[s];
      uint4 v = xwq[(size_t)s * 16 + sl];
      ACC8(v, o);
    }
  }
#undef ACC8

  a0 += __shfl_xor(a0, 16); a0 += __shfl_xor(a0, 32);
  a1 += __shfl_xor(a1, 16); a1 += __shfl_xor(a1, 32);
  a2 += __shfl_xor(a2, 16); a2 += __shfl_xor(a2, 32);
  a3 += __shfl_xor(a3, 16); a3 += __shfl_xor(a3, 32);
  a4 += __shfl_xor(a4, 16); a4 += __shfl_xor(a4, 32);
  a5 += __shfl_xor(a5, 16); a5 += __shfl_xor(a5, 32);
  a6 += __shfl_xor(a6, 16); a6 += __shfl_xor(a6, 32);
  a7 += __shfl_xor(a7, 16); a7 += __shfl_xor(a7, 32);

  float inI = invI[i];
  int f = sl * 8;
  float4 bl = *(const float4*)&b1[f];
  float4 bh = *(const float4*)&b1[f + 4];
  float4 wl = *(const float4*)&W2[f];
  float4 wh = *(const float4*)&W2[f + 4];
  float p = fmaxf(fmaf(a0, inI, bl.x), 0.f) * wl.x
          + fmaxf(fmaf(a1, inI, bl.y), 0.f) * wl.y
          + fmaxf(fmaf(a2, inI, bl.z), 0.f) * wl.z
          + fmaxf(fmaf(a3, inI, bl.w), 0.f) * wl.w
          + fmaxf(fmaf(a4, inI, bh.x), 0.f) * wh.x
          + fmaxf(fmaf(a5, inI, bh.y), 0.f) * wh.y
          + fmaxf(fmaf(a6, inI, bh.z), 0.f) * wh.z
          + fmaxf(fmaf(a7, inI, bh.w), 0.f) * wh.w;
#pragma unroll
  for (int off = 8; off; off >>= 1) p += __shfl_xor(p, off);
  if (lane == 0) h2[i] = p * invO[i];
}

// ---------------- layer-2 gather + epilogue (4 lanes per node) ----------------
__global__ __launch_bounds__(256) void k_gather2(const float* __restrict__ h2,
                                                 const int* __restrict__ rowoff,
                                                 const int* __restrict__ csr,
                                                 const float* __restrict__ invI,
                                                 const float* __restrict__ b2,
                                                 float* __restrict__ out, int N) {
  int i = blockIdx.x * 64 + (threadIdx.x >> 2);
  int q = threadIdx.x & 3;
  if (i >= N) return;
  int jb = rowoff[i];
  int je = rowoff[i + 1];
  float s = 0.f;
  for (int j = jb + q; j < je; j += 4) s += h2[csr[j]];
  s += __shfl_xor(s, 1);
  s += __shfl_xor(s, 2);
  if (q == 0) out[i] = s * invI[i] + b2[0];
}

extern "C" void kernel_launch(void* const* d_in, const int* in_sizes, int n_in,
                              void* d_out, int out_size, void* d_ws, size_t ws_size,
                              hipStream_t stream) {
  const float* x   = (const float*)d_in[0];
  const int*   src = (const int*)d_in[1];
  const int*   dst = (const int*)d_in[2];
  const float* W1  = (const float*)d_in[3];
  const float* b1  = (const float*)d_in[4];
  const float* W2  = (const float*)d_in[5];
  const float* b2  = (const float*)d_in[6];
  int N = in_sizes[0] / NF;
  int E = in_sizes[1];
  int NB = (N + 255) >> 8;             // <= 512

  int* bucketCnt  = (int*)d_ws;                    // 512
  int* bucketCntS = bucketCnt + 512;               // 512
  int* rowoff     = bucketCntS + 512;              // N+1 (pad to N+8)
  int* csr        = rowoff + (size_t)N + 8;        // E
  int2* region    = (int2*)(csr + (size_t)E);      // NB*CAP int2
  int* regionS    = (int*)(region + (size_t)NB * CAP);  // NB*CAP int
  float* invO     = (float*)(regionS + (size_t)NB * CAP);
  float* invI     = invO + N;
  float* h2       = invI + N;
  unsigned short* xw = (unsigned short*)(h2 + N);  // N*128 bf16
  float* out      = (float*)d_out;

  int B1 = (E + EPB - 1) / EPB;        // binA role blocks
  int B2 = (E + EPB2 - 1) / EPB2;      // binA2 role blocks
  int G  = ((N + 63) / 64) * 2;        // gemm role blocks

  k_init<<<1, 256, 0, stream>>>(bucketCnt, bucketCntS, rowoff, N, E);
  k_frontA<<<B1 + B2, 256, 0, stream>>>(src, dst, bucketCnt, bucketCntS,
                                        region, regionS, E, B1);
  k_mid<<<2 * NB + G, 256, 0, stream>>>(x, W1, region, bucketCnt, regionS, bucketCntS,
                                        csr, rowoff, invI, invO, xw, N, NB);
  k_gather_proj<<<(N + 3) / 4, 256, 0, stream>>>(xw, rowoff, csr, invI, invO, b1, W2, h2, N);
  k_gather2<<<(N + 63) / 64, 256, 0, stream>>>(h2, rowoff, csr, invI, b2, out, N);
}

// Round 15
// 174.850 us; speedup vs baseline: 1.5475x; 1.1802x over previous
//
#include <hip/hip_runtime.h>
#include <hip/hip_bf16.h>

#define NF 128
#define EPB 4096      // edges per binA role block (int2 staging, 32 KB)
#define EPB2 8192     // edges per binA2 role block (int staging, 32 KB)
#define CAP 6144      // per-bucket region capacity (mean 4096, +32 sigma)

typedef __attribute__((ext_vector_type(8))) short short8;   // 8 bf16 (4 VGPRs)
typedef __attribute__((ext_vector_type(4))) float f32x4;    // MFMA acc

// ---------------- init (1 block) ----------------
__global__ void k_init(int* __restrict__ bucketCnt, int* __restrict__ bucketCntS,
                       int* __restrict__ rowoff, int N, int E) {
  int i = threadIdx.x;
  for (int k = i; k < 512; k += 256) { bucketCnt[k] = 0; bucketCntS[k] = 0; }
  if (i == 0) rowoff[N] = E;
}

// ---------------- frontA: binA | binA2 (both memory-bound binning) ----------------
__global__ __launch_bounds__(256) void k_frontA(const int* __restrict__ src,
                                                const int* __restrict__ dst,
                                                int* __restrict__ bucketCnt,
                                                int* __restrict__ bucketCntS,
                                                int2* __restrict__ region,
                                                int* __restrict__ regionS,
                                                int E, int B1) {
  __shared__ __align__(16) char smem_raw[42240];  // 9216 ctl + 32768 staging
  int* cnt   = (int*)smem_raw;
  int* scanv = cnt + 512;
  int* cur   = scanv + 512;
  int* gb    = cur + 512;
  int* s1    = gb + 512;
  void* stv  = (void*)(smem_raw + 9216 + 256);  // 16B-aligned staging
  int tid = threadIdx.x;
  int b = blockIdx.x;

  if (b < B1) {
    // ---- binA role: bin (dst,src) pairs into 256-node buckets ----
    int2* st = (int2*)stv;
    int b0 = b * EPB;
    int n = E - b0; if (n > EPB) n = EPB;

    for (int k = tid; k < 512; k += 256) cnt[k] = 0;
    __syncthreads();
    for (int k = tid; k < n; k += 256) atomicAdd(&cnt[dst[b0 + k] >> 8], 1);
    __syncthreads();

    int c0 = cnt[2 * tid], c1 = cnt[2 * tid + 1];
    s1[tid] = c0 + c1;
    __syncthreads();
    for (int off = 1; off < 256; off <<= 1) {
      int v = (tid >= off) ? s1[tid - off] : 0;
      __syncthreads();
      s1[tid] += v;
      __syncthreads();
    }
    int excl = tid ? s1[tid - 1] : 0;
    scanv[2 * tid] = excl;
    scanv[2 * tid + 1] = excl + c0;
    cur[2 * tid] = excl;
    cur[2 * tid + 1] = excl + c0;
    gb[2 * tid]     = c0 ? atomicAdd(&bucketCnt[2 * tid], c0) : 0;
    gb[2 * tid + 1] = c1 ? atomicAdd(&bucketCnt[2 * tid + 1], c1) : 0;
    __syncthreads();

    for (int k = tid; k < n; k += 256) {
      int d = dst[b0 + k], s = src[b0 + k];
      int p = atomicAdd(&cur[d >> 8], 1);
      st[p] = make_int2(d, s);
    }
    __syncthreads();
    for (int k = tid; k < n; k += 256) {
      int2 e = st[k];
      int bk = e.x >> 8;
      int gp = gb[bk] + (k - scanv[bk]);
      if (gp < CAP) region[(size_t)bk * CAP + gp] = e;
    }
    return;
  }

  // ---- binA2 role: bin bare src values (out-degree) ----
  int* st = (int*)stv;
  int b0 = (b - B1) * EPB2;
  int n = E - b0; if (n > EPB2) n = EPB2;

  for (int k = tid; k < 512; k += 256) cnt[k] = 0;
  __syncthreads();
  for (int k = tid; k < n; k += 256) atomicAdd(&cnt[src[b0 + k] >> 8], 1);
  __syncthreads();

  int c0 = cnt[2 * tid], c1 = cnt[2 * tid + 1];
  s1[tid] = c0 + c1;
  __syncthreads();
  for (int off = 1; off < 256; off <<= 1) {
    int v = (tid >= off) ? s1[tid - off] : 0;
    __syncthreads();
    s1[tid] += v;
    __syncthreads();
  }
  int excl = tid ? s1[tid - 1] : 0;
  scanv[2 * tid] = excl;
  scanv[2 * tid + 1] = excl + c0;
  cur[2 * tid] = excl;
  cur[2 * tid + 1] = excl + c0;
  gb[2 * tid]     = c0 ? atomicAdd(&bucketCntS[2 * tid], c0) : 0;
  gb[2 * tid + 1] = c1 ? atomicAdd(&bucketCntS[2 * tid + 1], c1) : 0;
  __syncthreads();

  for (int k = tid; k < n; k += 256) {
    int s = src[b0 + k];
    int p = atomicAdd(&cur[s >> 8], 1);
    st[p] = s;
  }
  __syncthreads();
  for (int k = tid; k < n; k += 256) {
    int s = st[k];
    int bk = s >> 8;
    int gp = gb[bk] + (k - scanv[bk]);
    if (gp < CAP) regionS[(size_t)bk * CAP + gp] = s;
  }
}

// ---------------- mid: binB | binB2 | MFMA gemm1 ----------------
// LDS (gemm role): Wb = bf16 W1^T [128 n][136 k] (34816 B), Xb = bf16 x-tile [64][136] (17408 B)
__global__ __launch_bounds__(256) void k_mid(const float* __restrict__ x,
                                             const float* __restrict__ W1,
                                             const int2* __restrict__ region,
                                             const int* __restrict__ bucketCnt,
                                             const int* __restrict__ regionS,
                                             const int* __restrict__ bucketCntS,
                                             int* __restrict__ csr,
                                             int* __restrict__ rowoff,
                                             float* __restrict__ invI,
                                             float* __restrict__ invO,
                                             unsigned short* __restrict__ xw,
                                             int N, int NB) {
  __shared__ __align__(16) char smem_raw[52224];
  int tid = threadIdx.x;
  int blk = blockIdx.x;

  if (blk < NB) {
    // ---- binB role: counting sort -> csr + rowoff + invI ----
    int* s1   = (int*)smem_raw;
    int* hist = s1 + 256;
    int* incl = hist + 256;
    int* cur  = incl + 256;
    int b = blk;
    int c0 = (2 * tid < NB) ? bucketCnt[2 * tid] : 0;
    int c1 = (2 * tid + 1 < NB) ? bucketCnt[2 * tid + 1] : 0;
    s1[tid] = c0 + c1;
    __syncthreads();
    for (int off = 1; off < 256; off <<= 1) {
      int v = (tid >= off) ? s1[tid - off] : 0;
      __syncthreads();
      s1[tid] += v;
      __syncthreads();
    }
    int t = b >> 1;
    int csrBase = t ? s1[t - 1] : 0;
    if (b & 1) csrBase += bucketCnt[b & ~1];

    int base = b << 8;
    int nN = N - base; if (nN > 256) nN = 256;
    int cntb = bucketCnt[b]; if (cntb > CAP) cntb = CAP;
    const int2* reg = region + (size_t)b * CAP;

    hist[tid] = 0;
    __syncthreads();
    for (int k = tid; k < cntb; k += 256) atomicAdd(&hist[reg[k].x - base], 1);
    __syncthreads();
    int h = hist[tid];
    incl[tid] = h;
    __syncthreads();
    for (int off = 1; off < 256; off <<= 1) {
      int v = (tid >= off) ? incl[tid - off] : 0;
      __syncthreads();
      incl[tid] += v;
      __syncthreads();
    }
    int startt = incl[tid] - h;  // exclusive
    if (tid < nN) {
      rowoff[base + tid] = csrBase + startt;
      invI[base + tid] = rsqrtf(fmaxf((float)h, 1.0f));
    }
    cur[tid] = startt;
    __syncthreads();
    for (int k = tid; k < cntb; k += 256) {
      int2 e = reg[k];
      int p = atomicAdd(&cur[e.x - base], 1);
      csr[csrBase + p] = e.y;
    }
    return;
  }

  if (blk < 2 * NB) {
    // ---- binB2 role: src histogram -> invO ----
    int* hist = (int*)smem_raw;
    int b = blk - NB;
    int base = b << 8;
    int cntb = bucketCntS[b]; if (cntb > CAP) cntb = CAP;
    const int* reg = regionS + (size_t)b * CAP;
    hist[tid] = 0;
    __syncthreads();
    for (int k = tid; k < cntb; k += 256) atomicAdd(&hist[reg[k] - base], 1);
    __syncthreads();
    if (base + tid < N) invO[base + tid] = rsqrtf(fmaxf((float)hist[tid], 1.0f));
    return;
  }

  // ---- gemm role (MFMA): xw[64 rows] = bf16( x @ W1 ) ----
  unsigned short* Wb = (unsigned short*)smem_raw;   // [128][136]
  unsigned short* Xb = Wb + 128 * 136;              // [64][136]
  int idx = blk - 2 * NB;
  int rowbase = idx * 64;

  // stage W1^T: Wb[n][k] = bf16(W1[k][n]); coalesced global reads over n
  for (int t = tid; t < 128 * 128; t += 256) {
    int k = t >> 7, n = t & 127;
    __hip_bfloat16 hb = __float2bfloat16(W1[k * NF + n]);
    Wb[n * 136 + k] = *(unsigned short*)&hb;
  }
  // stage x tile: Xb[r][k] = bf16(x[rowbase+r][k]); float4 coalesced reads
  for (int t = tid; t < 64 * 32; t += 256) {
    int r = t >> 5, k4 = (t & 31) << 2;
    int row = rowbase + r; if (row >= N) row = N - 1;
    float4 v = *(const float4*)&x[(size_t)row * NF + k4];
    __hip_bfloat16 h0 = __float2bfloat16(v.x);
    __hip_bfloat16 h1 = __float2bfloat16(v.y);
    __hip_bfloat16 h2 = __float2bfloat16(v.z);
    __hip_bfloat16 h3 = __float2bfloat16(v.w);
    ushort4 u;
    u.x = *(unsigned short*)&h0;
    u.y = *(unsigned short*)&h1;
    u.z = *(unsigned short*)&h2;
    u.w = *(unsigned short*)&h3;
    *(ushort4*)&Xb[r * 136 + k4] = u;
  }
  __syncthreads();

  int w    = tid >> 6;   // wave 0..3 -> rows w*16..w*16+15
  int lane = tid & 63;
  int r16  = lane & 15;
  int kg   = lane >> 4;  // 0..3

  // A fragments (rows), one per K-step of 32
  short8 afrag[4];
#pragma unroll
  for (int kk = 0; kk < 4; ++kk) {
    afrag[kk] = *(const short8*)&Xb[(w * 16 + r16) * 136 + kg * 8 + kk * 32];
  }

#pragma unroll
  for (int ct = 0; ct < 8; ++ct) {
    f32x4 acc = {0.f, 0.f, 0.f, 0.f};
#pragma unroll
    for (int kk = 0; kk < 4; ++kk) {
      short8 bfrag = *(const short8*)&Wb[(ct * 16 + r16) * 136 + kg * 8 + kk * 32];
      acc = __builtin_amdgcn_mfma_f32_16x16x32_bf16(afrag[kk], bfrag, acc, 0, 0, 0);
    }
    // D: row = 4*kg + reg (within wave tile), col = ct*16 + r16
#pragma unroll
    for (int reg = 0; reg < 4; ++reg) {
      int row = rowbase + w * 16 + kg * 4 + reg;
      if (row < N) {
        __hip_bfloat16 hb = __float2bfloat16(acc[reg]);
        xw[(size_t)row * NF + ct * 16 + r16] = *(unsigned short*)&hb;
      }
    }
  }
}

// ---------------- fused gather + layer-2 projection (uint4 loads) ----------------
__global__ __launch_bounds__(256) void k_gather_proj(const unsigned short* __restrict__ xw,
                                                     const int* __restrict__ rowoff,
                                                     const int* __restrict__ csr,
                                                     const float* __restrict__ invI,
                                                     const float* __restrict__ invO,
                                                     const float* __restrict__ b1,
                                                     const float* __restrict__ W2,
                                                     float* __restrict__ h2, int N) {
  int i    = blockIdx.x * 4 + (threadIdx.x >> 6);
  int lane = threadIdx.x & 63;
  int grp  = lane >> 4;   // 0..3
  int sl   = lane & 15;
  if (i >= N) return;
  int jb = rowoff[i];
  int je = rowoff[i + 1];
  const uint4* xwq = (const uint4*)xw;  // 16 uint4 per row
  float a0 = 0.f, a1 = 0.f, a2 = 0.f, a3 = 0.f;
  float a4 = 0.f, a5 = 0.f, a6 = 0.f, a7 = 0.f;

#define ACC8(v, o)                                                         \
  do {                                                                     \
    a0 = fmaf(__uint_as_float(((v).x & 0xffffu) << 16), (o), a0);          \
    a1 = fmaf(__uint_as_float((v).x & 0xffff0000u), (o), a1);              \
    a2 = fmaf(__uint_as_float(((v).y & 0xffffu) << 16), (o), a2);          \
    a3 = fmaf(__uint_as_float((v).y & 0xffff0000u), (o), a3);              \
    a4 = fmaf(__uint_as_float(((v).z & 0xffffu) << 16), (o), a4);          \
    a5 = fmaf(__uint_as_float((v).z & 0xffff0000u), (o), a5);              \
    a6 = fmaf(__uint_as_float(((v).w & 0xffffu) << 16), (o), a6);          \
    a7 = fmaf(__uint_as_float((v).w & 0xffff0000u), (o), a7);              \
  } while (0)

  int j = jb;
  for (; j + 8 <= je; j += 8) {
    int s0 = csr[j + grp];
    int s1 = csr[j + 4 + grp];
    float o0 = invO[s0], o1 = invO[s1];
    uint4 v0 = xwq[(size_t)s0 * 16 + sl];
    uint4 v1 = xwq[(size_t)s1 * 16 + sl];
    ACC8(v0, o0);
    ACC8(v1, o1);
  }
  for (; j < je; j += 4) {
    int e = j + grp;
    if (e < je) {
      int s = csr[e];
      float o = invO[s];
      uint4 v = xwq[(size_t)s * 16 + sl];
      ACC8(v, o);
    }
  }
#undef ACC8

  a0 += __shfl_xor(a0, 16); a0 += __shfl_xor(a0, 32);
  a1 += __shfl_xor(a1, 16); a1 += __shfl_xor(a1, 32);
  a2 += __shfl_xor(a2, 16); a2 += __shfl_xor(a2, 32);
  a3 += __shfl_xor(a3, 16); a3 += __shfl_xor(a3, 32);
  a4 += __shfl_xor(a4, 16); a4 += __shfl_xor(a4, 32);
  a5 += __shfl_xor(a5, 16); a5 += __shfl_xor(a5, 32);
  a6 += __shfl_xor(a6, 16); a6 += __shfl_xor(a6, 32);
  a7 += __shfl_xor(a7, 16); a7 += __shfl_xor(a7, 32);

  float inI = invI[i];
  int f = sl * 8;
  float4 bl = *(const float4*)&b1[f];
  float4 bh = *(const float4*)&b1[f + 4];
  float4 wl = *(const float4*)&W2[f];
  float4 wh = *(const float4*)&W2[f + 4];
  float p = fmaxf(fmaf(a0, inI, bl.x), 0.f) * wl.x
          + fmaxf(fmaf(a1, inI, bl.y), 0.f) * wl.y
          + fmaxf(fmaf(a2, inI, bl.z), 0.f) * wl.z
          + fmaxf(fmaf(a3, inI, bl.w), 0.f) * wl.w
          + fmaxf(fmaf(a4, inI, bh.x), 0.f) * wh.x
          + fmaxf(fmaf(a5, inI, bh.y), 0.f) * wh.y
          + fmaxf(fmaf(a6, inI, bh.z), 0.f) * wh.z
          + fmaxf(fmaf(a7, inI, bh.w), 0.f) * wh.w;
#pragma unroll
  for (int off = 8; off; off >>= 1) p += __shfl_xor(p, off);
  if (lane == 0) h2[i] = p * invO[i];
}

// ---------------- layer-2 gather + epilogue (4 lanes per node) ----------------
__global__ __launch_bounds__(256) void k_gather2(const float* __restrict__ h2,
                                                 const int* __restrict__ rowoff,
                                                 const int* __restrict__ csr,
                                                 const float* __restrict__ invI,
                                                 const float* __restrict__ b2,
                                                 float* __restrict__ out, int N) {
  int i = blockIdx.x * 64 + (threadIdx.x >> 2);
  int q = threadIdx.x & 3;
  if (i >= N) return;
  int jb = rowoff[i];
  int je = rowoff[i + 1];
  float s = 0.f;
  for (int j = jb + q; j < je; j += 4) s += h2[csr[j]];
  s += __shfl_xor(s, 1);
  s += __shfl_xor(s, 2);
  if (q == 0) out[i] = s * invI[i] + b2[0];
}

extern "C" void kernel_launch(void* const* d_in, const int* in_sizes, int n_in,
                              void* d_out, int out_size, void* d_ws, size_t ws_size,
                              hipStream_t stream) {
  const float* x   = (const float*)d_in[0];
  const int*   src = (const int*)d_in[1];
  const int*   dst = (const int*)d_in[2];
  const float* W1  = (const float*)d_in[3];
  const float* b1  = (const float*)d_in[4];
  const float* W2  = (const float*)d_in[5];
  const float* b2  = (const float*)d_in[6];
  int N = in_sizes[0] / NF;
  int E = in_sizes[1];
  int NB = (N + 255) >> 8;             // <= 512

  int* bucketCnt  = (int*)d_ws;                    // 512
  int* bucketCntS = bucketCnt + 512;               // 512
  int* rowoff     = bucketCntS + 512;              // N+1 (pad to N+8)
  int* csr        = rowoff + (size_t)N + 8;        // E
  int2* region    = (int2*)(csr + (size_t)E);      // NB*CAP int2
  int* regionS    = (int*)(region + (size_t)NB * CAP);  // NB*CAP int
  float* invO     = (float*)(regionS + (size_t)NB * CAP);
  float* invI     = invO + N;
  float* h2       = invI + N;
  unsigned short* xw = (unsigned short*)(h2 + N);  // N*128 bf16
  float* out      = (float*)d_out;

  int B1 = (E + EPB - 1) / EPB;        // binA role blocks
  int B2 = (E + EPB2 - 1) / EPB2;      // binA2 role blocks
  int G  = (N + 63) / 64;              // MFMA gemm role blocks

  k_init<<<1, 256, 0, stream>>>(bucketCnt, bucketCntS, rowoff, N, E);
  k_frontA<<<B1 + B2, 256, 0, stream>>>(src, dst, bucketCnt, bucketCntS,
                                        region, regionS, E, B1);
  k_mid<<<2 * NB + G, 256, 0, stream>>>(x, W1, region, bucketCnt, regionS, bucketCntS,
                                        csr, rowoff, invI, invO, xw, N, NB);
  k_gather_proj<<<(N + 3) / 4, 256, 0, stream>>>(xw, rowoff, csr, invI, invO, b1, W2, h2, N);
  k_gather2<<<(N + 63) / 64, 256, 0, stream>>>(h2, rowoff, csr, invI, b2, out, N);
}